// Round 19
// baseline (309.198 us; speedup 1.0000x reference)
//
#include <hip/hip_runtime.h>
#include <math.h>

typedef _Float16 f16x8 __attribute__((ext_vector_type(8)));
typedef _Float16 f16x4 __attribute__((ext_vector_type(4)));
typedef float f32x4 __attribute__((ext_vector_type(4)));

#define MFMA16(a, b, c) __builtin_amdgcn_mfma_f32_16x16x32_f16(a, b, c, 0, 0, 0)

constexpr int L = 1024;
constexpr int D = 64;
constexpr int BH = 128;                       // B*H
constexpr size_t OUT_ELEMS = 8ull * 16 * 1024 * 64;
constexpr size_t PLANE = (size_t)BH * L * D;  // 8,388,608 elems
constexpr size_t BMN   = 8ull * 1024 * 1024;  // B*L*L elems

// fp16-element LDS swizzle: XOR col bits [3:5] (16B blocks) with row&7
__device__ __forceinline__ int swzh(int row, int col) {
    return row * L + (col ^ ((row & 7) << 3));
}

// ---------------- fused prep kernel: XCD-co-located with consumer (R18) ----------------
__global__ __launch_bounds__(256)
void prep_all(const float* __restrict__ kg, const float* __restrict__ vg,
              const float* __restrict__ bias, const int* __restrict__ mask,
              _Float16* __restrict__ kf, _Float16* __restrict__ vtf,
              _Float16* __restrict__ bmp) {
    __shared__ __align__(16) char smem[16640];
    const int p = blockIdx.x;
    const int tid = threadIdx.x;

    if (p < 2048) {
        // ---- bm section: region per (b,qt32,w): 4096 fp16 ----
        const int g = p & 7, i = p >> 3;
        const int wgid = g * 256 + i;         // (b*32+qt)*8 + w, b == g
        float (*tile)[132] = (float(*)[132])smem;
        const int w    = wgid & 7;
        const int bqt  = wgid >> 3;
        const int qt = bqt & 31;
        const int b  = bqt >> 5;
        _Float16* outr = bmp + (size_t)wgid * 4096;
#pragma unroll 1
        for (int half = 0; half < 2; ++half) {
            const size_t rowbase = ((size_t)b * L + qt * 32 + half * 16) * L + w * 128;
#pragma unroll
            for (int h = 0; h < 8; ++h) {
                const int idx = h * 256 + tid;
                const int row = idx >> 7, col = idx & 127;
                float bv = bias[rowbase + (size_t)row * L + col];
                int   mv = mask[rowbase + (size_t)row * L + col];
                tile[row][col] = mv ? bv : -1.0f;
            }
            __syncthreads();
            const int lam = tid & 63;
            const int lr = lam & 15, lg = lam >> 4;
            const int gg = tid >> 6;          // 0..3
            f16x8 o;
#pragma unroll
            for (int s = 0; s < 8; ++s) {
                const int slot = gg * 8 + s;  // = ct*4 + r, ct in [0,8)
                const int ct = slot >> 2, r = slot & 3;
                o[s] = (_Float16)tile[lr][ct * 16 + 4 * lg + r];
            }
            *(f16x8*)(outr + half * 2048 + (size_t)tid * 8) = o;
            __syncthreads();
        }
    } else if (p < 4096) {
        // ---- V section: V [bh][k][d] -> fp16 Vt [bh][d][k] ----
        const int ps = p - 2048;
        const int g = ps & 7, i = ps >> 3;
        const int vb = g * 256 + i;
        _Float16 (*tile)[72] = (_Float16(*)[72])smem;
        const int bh = vb >> 4;
        const int k0 = (vb & 15) * 64;
#pragma unroll
        for (int r = 0; r < 4; ++r) {
            const int k  = r * 16 + (tid >> 4);
            const int d0 = (tid & 15) * 4;
            float4 a = *(const float4*)(vg + ((size_t)(bh * L + k0 + k)) * D + d0);
            tile[d0 + 0][k] = (_Float16)a.x;
            tile[d0 + 1][k] = (_Float16)a.y;
            tile[d0 + 2][k] = (_Float16)a.z;
            tile[d0 + 3][k] = (_Float16)a.w;
        }
        __syncthreads();
#pragma unroll
        for (int w = 0; w < 4; ++w) {
            const int d   = w * 16 + (tid >> 4);
            const int kk0 = (tid & 15) * 4;
            const size_t dst = (size_t)bh * (D * L) + (size_t)d * L + k0 + kk0;
            *(f16x4*)(vtf + dst) = *(const f16x4*)&tile[d][kk0];
        }
    } else {
        // ---- K section: K -> fp16 plane (0.125 folded) ----
        const int ps = p - 4096;
        const int g = ps & 7, i = ps >> 3;
        const int kbid = g * 512 + i;
        const size_t t = ((size_t)kbid * 256 + tid) * 8;
        float4 a0 = *(const float4*)(kg + t);
        float4 a1 = *(const float4*)(kg + t + 4);
        f16x8 o;
        o[0] = (_Float16)(0.125f * a0.x); o[1] = (_Float16)(0.125f * a0.y);
        o[2] = (_Float16)(0.125f * a0.z); o[3] = (_Float16)(0.125f * a0.w);
        o[4] = (_Float16)(0.125f * a1.x); o[5] = (_Float16)(0.125f * a1.y);
        o[6] = (_Float16)(0.125f * a1.z); o[7] = (_Float16)(0.125f * a1.w);
        *(f16x8*)(kf + t) = o;
    }
}

// ---- main kernel: QT=32 dual-tile; score stored direct-from-registers ----
__global__ __launch_bounds__(512, 4)
void attn_main(const float* __restrict__ qg, const _Float16* __restrict__ kf_g,
               const _Float16* __restrict__ vtf_g, const _Float16* __restrict__ bmp_g,
               float* __restrict__ outg) {
    __shared__ __align__(16) _Float16 plds[32 * L];   // 64 KiB P buffer
    __shared__ float red[8][32][2];                   // 2 KiB {m, sum}

    // bijective XCD swizzle: 4096 % 8 == 0
    const int wg = (blockIdx.x & 7) * 512 + (blockIdx.x >> 3);
    const int bh = wg >> 5;
    const int qt = wg & 31;
    const int b  = bh >> 4;
    const int q0 = qt * 32;
    const int tid  = threadIdx.x;
    const int wave = tid >> 6;                // 0..7
    const int lane = tid & 63;
    const int lg   = lane >> 4;
    const int lr   = lane & 15;

    const float*    qp = qg + (size_t)bh * L * D;
    const _Float16* kp = kf_g + (size_t)bh * L * D;
    const int kbase = wave * 128;

    // Q as B-frags for both 16-row subtiles
    f16x8 qf[2][2];
#pragma unroll
    for (int t = 0; t < 2; ++t) {
        const float* src = qp + (size_t)(q0 + t * 16 + lr) * D + lg * 8;
        float4 a0 = *(const float4*)src;
        float4 a1 = *(const float4*)(src + 4);
        float4 a2 = *(const float4*)(src + 32);
        float4 a3 = *(const float4*)(src + 36);
        qf[t][0][0] = (_Float16)a0.x; qf[t][0][1] = (_Float16)a0.y;
        qf[t][0][2] = (_Float16)a0.z; qf[t][0][3] = (_Float16)a0.w;
        qf[t][0][4] = (_Float16)a1.x; qf[t][0][5] = (_Float16)a1.y;
        qf[t][0][6] = (_Float16)a1.z; qf[t][0][7] = (_Float16)a1.w;
        qf[t][1][0] = (_Float16)a2.x; qf[t][1][1] = (_Float16)a2.y;
        qf[t][1][2] = (_Float16)a2.z; qf[t][1][3] = (_Float16)a2.w;
        qf[t][1][4] = (_Float16)a3.x; qf[t][1][5] = (_Float16)a3.y;
        qf[t][1][6] = (_Float16)a3.z; qf[t][1][7] = (_Float16)a3.w;
    }

    // ---- swapped QK^T, K loads shared across both q-subtiles ----
    f32x4 acc[2][8];
    __builtin_amdgcn_s_setprio(1);
#pragma unroll
    for (int ct = 0; ct < 8; ++ct) {
        const _Float16* krow = kp + (size_t)(kbase + ct * 16 + lr) * D + lg * 8;
        f16x8 kv0 = *(const f16x8*)(krow);
        f16x8 kv1 = *(const f16x8*)(krow + 32);
#pragma unroll
        for (int t = 0; t < 2; ++t) {
            f32x4 a = {0.f, 0.f, 0.f, 0.f};
            a = MFMA16(kv0, qf[t][0], a);
            a = MFMA16(kv1, qf[t][1], a);
            acc[t][ct] = a;
        }
    }
    __builtin_amdgcn_s_setprio(0);

    // ---- bias*mask apply ----
    const _Float16* bmr = bmp_g + ((size_t)(b * 32 + qt) * 8 + wave) * 4096;
#pragma unroll
    for (int t = 0; t < 2; ++t) {
#pragma unroll
        for (int g = 0; g < 4; ++g) {
            f16x8 bv = *(const f16x8*)(bmr + t * 2048 + g * 512 + lane * 8);
#pragma unroll
            for (int s = 0; s < 8; ++s) {
                const int slot = g * 8 + s;
                float tt = (float)bv[s];
                float a = acc[t][slot >> 2][slot & 3];
                acc[t][slot >> 2][slot & 3] = (tt >= 0.f) ? a * tt : -INFINITY;
            }
        }
    }

    // ---- two independent in-register softmax chains (ILP) ----
    float m[2], ls[2];
#pragma unroll
    for (int t = 0; t < 2; ++t) m[t] = -INFINITY;
#pragma unroll
    for (int ct = 0; ct < 8; ++ct)
#pragma unroll
        for (int t = 0; t < 2; ++t)
#pragma unroll
            for (int r = 0; r < 4; ++r) m[t] = fmaxf(m[t], acc[t][ct][r]);
#pragma unroll
    for (int t = 0; t < 2; ++t) {
        m[t] = fmaxf(m[t], __shfl_xor(m[t], 16));
        m[t] = fmaxf(m[t], __shfl_xor(m[t], 32));
        m[t] = fmaxf(m[t], -10000.0f);        // guard all-masked chunk
        ls[t] = 0.f;
    }
#pragma unroll
    for (int ct = 0; ct < 8; ++ct)
#pragma unroll
        for (int t = 0; t < 2; ++t)
#pragma unroll
            for (int r = 0; r < 4; ++r) {
                float p = __expf(acc[t][ct][r] - m[t]);
                acc[t][ct][r] = p;
                ls[t] += p;
            }
#pragma unroll
    for (int t = 0; t < 2; ++t) {
        ls[t] += __shfl_xor(ls[t], 16);
        ls[t] += __shfl_xor(ls[t], 32);
    }

    // ---- cross-wave reduction ----
    if (lg == 0) {
#pragma unroll
        for (int t = 0; t < 2; ++t) {
            red[wave][t * 16 + lr][0] = m[t];
            red[wave][t * 16 + lr][1] = ls[t];
        }
    }
    __syncthreads();                          // barrier 1: red ready

    float scale[2];
#pragma unroll
    for (int t = 0; t < 2; ++t) {
        const int row = t * 16 + lr;
        float M = -INFINITY;
#pragma unroll
        for (int w = 0; w < 8; ++w) M = fmaxf(M, red[w][row][0]);
        float denom = 0.f;
#pragma unroll
        for (int w = 0; w < 8; ++w) denom += red[w][row][1] * __expf(red[w][row][0] - M);
        denom = fmaxf(denom, 1e-37f);
        scale[t] = __expf(m[t] - M) / denom;
    }

    // ---- score store DIRECT FROM REGISTERS (f32-exact, NT), before barrier 2.
    // D-frag layout: q-row = q0+t*16+lr, key-col = kbase+ct*16+lg*4+r.
    // Per (t,ct): wave covers 16 rows x 64B contiguous segments; NT stream
    // drains under P-write + barrier + PV below.
    float* score = outg + OUT_ELEMS + (size_t)bh * L * L;
#pragma unroll
    for (int t = 0; t < 2; ++t) {
        float* srow = score + (size_t)(q0 + t * 16 + lr) * L + kbase + lg * 4;
#pragma unroll
        for (int ct = 0; ct < 8; ++ct) {
            f32x4 o = {acc[t][ct][0] * scale[t], acc[t][ct][1] * scale[t],
                       acc[t][ct][2] * scale[t], acc[t][ct][3] * scale[t]};
            __builtin_nontemporal_store(o, (f32x4*)(srow + ct * 16));
        }
    }

    // ---- P -> LDS fp16 (normalized) ----
#pragma unroll
    for (int t = 0; t < 2; ++t)
#pragma unroll
        for (int ct = 0; ct < 8; ++ct) {
            f16x4 pv;
#pragma unroll
            for (int r = 0; r < 4; ++r) pv[r] = (_Float16)(acc[t][ct][r] * scale[t]);
            *(f16x4*)&plds[swzh(t * 16 + lr, kbase + ct * 16 + 4 * lg)] = pv;
        }
    __syncthreads();                          // barrier 2: P ready

    // ---- PV: wave w -> (q-subtile w>>2, d cols 16*(w&3)..+16) ----
    const int qsub = wave >> 2;
    const int d0   = (wave & 3) * 16;
    const _Float16* vrow = vtf_g + (size_t)bh * D * L + (size_t)(d0 + lr) * L;
    f32x4 oacc = {0.f, 0.f, 0.f, 0.f};
    __builtin_amdgcn_s_setprio(1);
#pragma unroll
    for (int kb = 0; kb < L; kb += 32) {
        const int e0 = kb + lg * 8;
        f16x8 pa = *(const f16x8*)&plds[swzh(qsub * 16 + lr, e0)];
        f16x8 vb = *(const f16x8*)(vrow + e0);
        oacc = MFMA16(pa, vb, oacc);
    }
    __builtin_amdgcn_s_setprio(0);
#pragma unroll
    for (int r = 0; r < 4; ++r) {
        __builtin_nontemporal_store(
            oacc[r], outg + ((size_t)bh * L + q0 + qsub * 16 + lg * 4 + r) * D + d0 + lr);
    }
}

extern "C" void kernel_launch(void* const* d_in, const int* in_sizes, int n_in,
                              void* d_out, int out_size, void* d_ws, size_t ws_size,
                              hipStream_t stream) {
    const float* q    = (const float*)d_in[0];
    const float* k    = (const float*)d_in[1];
    const float* v    = (const float*)d_in[2];
    const float* bias = (const float*)d_in[3];
    const int*   mask = (const int*)d_in[4];
    float* out = (float*)d_out;

    const size_t need = (2 * PLANE + BMN) * sizeof(_Float16);   // ~50 MiB
    if (ws_size < need) return;               // empirically ws_size >= 64 MiB

    _Float16* kf  = (_Float16*)d_ws;          // [BH][L][D] fp16, pre-scaled 0.125
    _Float16* vtf = kf + PLANE;               // [BH][D][L] fp16
    _Float16* bmp = vtf + PLANE;              // permuted fp16 bias/mask plane

    hipLaunchKernelGGL(prep_all, dim3(8192), dim3(256), 0, stream,
                       k, v, bias, mask, kf, vtf, bmp);
    hipLaunchKernelGGL(attn_main, dim3(4096), dim3(512), 0, stream,
                       q, kf, vtf, bmp, out);
}

// Round 20
// 273.073 us; speedup vs baseline: 1.1323x; 1.1323x over previous
//
#include <hip/hip_runtime.h>
#include <math.h>

typedef _Float16 f16x8 __attribute__((ext_vector_type(8)));
typedef _Float16 f16x4 __attribute__((ext_vector_type(4)));
typedef float f32x4 __attribute__((ext_vector_type(4)));

#define MFMA16(a, b, c) __builtin_amdgcn_mfma_f32_16x16x32_f16(a, b, c, 0, 0, 0)

constexpr int L = 1024;
constexpr int D = 64;
constexpr int BH = 128;                       // B*H
constexpr size_t OUT_ELEMS = 8ull * 16 * 1024 * 64;
constexpr size_t PLANE = (size_t)BH * L * D;  // 8,388,608 elems
constexpr size_t BMN   = 8ull * 1024 * 1024;  // B*L*L elems

// fp16-element LDS swizzle: XOR col bits [3:5] (16B blocks) with row&7
__device__ __forceinline__ int swzh(int row, int col) {
    return row * L + (col ^ ((row & 7) << 3));
}

// ---------------- fused prep kernel: XCD-co-located with consumer (R18) ----------------
__global__ __launch_bounds__(256)
void prep_all(const float* __restrict__ kg, const float* __restrict__ vg,
              const float* __restrict__ bias, const int* __restrict__ mask,
              _Float16* __restrict__ kf, _Float16* __restrict__ vtf,
              _Float16* __restrict__ bmp) {
    __shared__ __align__(16) char smem[16640];
    const int p = blockIdx.x;
    const int tid = threadIdx.x;

    if (p < 2048) {
        // ---- bm section: region per (b,qt32,w): 4096 fp16 ----
        const int g = p & 7, i = p >> 3;
        const int wgid = g * 256 + i;         // (b*32+qt)*8 + w, b == g
        float (*tile)[132] = (float(*)[132])smem;
        const int w    = wgid & 7;
        const int bqt  = wgid >> 3;
        const int qt = bqt & 31;
        const int b  = bqt >> 5;
        _Float16* outr = bmp + (size_t)wgid * 4096;
#pragma unroll 1
        for (int half = 0; half < 2; ++half) {
            const size_t rowbase = ((size_t)b * L + qt * 32 + half * 16) * L + w * 128;
#pragma unroll
            for (int h = 0; h < 8; ++h) {
                const int idx = h * 256 + tid;
                const int row = idx >> 7, col = idx & 127;
                float bv = bias[rowbase + (size_t)row * L + col];
                int   mv = mask[rowbase + (size_t)row * L + col];
                tile[row][col] = mv ? bv : -1.0f;
            }
            __syncthreads();
            const int lam = tid & 63;
            const int lr = lam & 15, lg = lam >> 4;
            const int gg = tid >> 6;          // 0..3
            f16x8 o;
#pragma unroll
            for (int s = 0; s < 8; ++s) {
                const int slot = gg * 8 + s;  // = ct*4 + r, ct in [0,8)
                const int ct = slot >> 2, r = slot & 3;
                o[s] = (_Float16)tile[lr][ct * 16 + 4 * lg + r];
            }
            *(f16x8*)(outr + half * 2048 + (size_t)tid * 8) = o;
            __syncthreads();
        }
    } else if (p < 4096) {
        // ---- V section: V [bh][k][d] -> fp16 Vt [bh][d][k] ----
        const int ps = p - 2048;
        const int g = ps & 7, i = ps >> 3;
        const int vb = g * 256 + i;
        _Float16 (*tile)[72] = (_Float16(*)[72])smem;
        const int bh = vb >> 4;
        const int k0 = (vb & 15) * 64;
#pragma unroll
        for (int r = 0; r < 4; ++r) {
            const int k  = r * 16 + (tid >> 4);
            const int d0 = (tid & 15) * 4;
            float4 a = *(const float4*)(vg + ((size_t)(bh * L + k0 + k)) * D + d0);
            tile[d0 + 0][k] = (_Float16)a.x;
            tile[d0 + 1][k] = (_Float16)a.y;
            tile[d0 + 2][k] = (_Float16)a.z;
            tile[d0 + 3][k] = (_Float16)a.w;
        }
        __syncthreads();
#pragma unroll
        for (int w = 0; w < 4; ++w) {
            const int d   = w * 16 + (tid >> 4);
            const int kk0 = (tid & 15) * 4;
            const size_t dst = (size_t)bh * (D * L) + (size_t)d * L + k0 + kk0;
            *(f16x4*)(vtf + dst) = *(const f16x4*)&tile[d][kk0];
        }
    } else {
        // ---- K section: K -> fp16 plane (0.125 folded) ----
        const int ps = p - 4096;
        const int g = ps & 7, i = ps >> 3;
        const int kbid = g * 512 + i;
        const size_t t = ((size_t)kbid * 256 + tid) * 8;
        float4 a0 = *(const float4*)(kg + t);
        float4 a1 = *(const float4*)(kg + t + 4);
        f16x8 o;
        o[0] = (_Float16)(0.125f * a0.x); o[1] = (_Float16)(0.125f * a0.y);
        o[2] = (_Float16)(0.125f * a0.z); o[3] = (_Float16)(0.125f * a0.w);
        o[4] = (_Float16)(0.125f * a1.x); o[5] = (_Float16)(0.125f * a1.y);
        o[6] = (_Float16)(0.125f * a1.z); o[7] = (_Float16)(0.125f * a1.w);
        *(f16x8*)(kf + t) = o;
    }
}

// ---- main kernel: R18 + V-ring prefetch issued BEFORE score stores ----
__global__ __launch_bounds__(512, 4)
void attn_main(const float* __restrict__ qg, const _Float16* __restrict__ kf_g,
               const _Float16* __restrict__ vtf_g, const _Float16* __restrict__ bmp_g,
               float* __restrict__ outg) {
    __shared__ __align__(16) _Float16 plds[32 * L];   // 64 KiB P buffer
    __shared__ float red[8][32][2];                   // 2 KiB {m, sum}

    // bijective XCD swizzle: 4096 % 8 == 0
    const int wg = (blockIdx.x & 7) * 512 + (blockIdx.x >> 3);
    const int bh = wg >> 5;
    const int qt = wg & 31;
    const int b  = bh >> 4;
    const int q0 = qt * 32;
    const int tid  = threadIdx.x;
    const int wave = tid >> 6;                // 0..7
    const int lane = tid & 63;
    const int lg   = lane >> 4;
    const int lr   = lane & 15;

    const float*    qp = qg + (size_t)bh * L * D;
    const _Float16* kp = kf_g + (size_t)bh * L * D;
    const int kbase = wave * 128;

    // Q as B-frags for both 16-row subtiles
    f16x8 qf[2][2];
#pragma unroll
    for (int t = 0; t < 2; ++t) {
        const float* src = qp + (size_t)(q0 + t * 16 + lr) * D + lg * 8;
        float4 a0 = *(const float4*)src;
        float4 a1 = *(const float4*)(src + 4);
        float4 a2 = *(const float4*)(src + 32);
        float4 a3 = *(const float4*)(src + 36);
        qf[t][0][0] = (_Float16)a0.x; qf[t][0][1] = (_Float16)a0.y;
        qf[t][0][2] = (_Float16)a0.z; qf[t][0][3] = (_Float16)a0.w;
        qf[t][0][4] = (_Float16)a1.x; qf[t][0][5] = (_Float16)a1.y;
        qf[t][0][6] = (_Float16)a1.z; qf[t][0][7] = (_Float16)a1.w;
        qf[t][1][0] = (_Float16)a2.x; qf[t][1][1] = (_Float16)a2.y;
        qf[t][1][2] = (_Float16)a2.z; qf[t][1][3] = (_Float16)a2.w;
        qf[t][1][4] = (_Float16)a3.x; qf[t][1][5] = (_Float16)a3.y;
        qf[t][1][6] = (_Float16)a3.z; qf[t][1][7] = (_Float16)a3.w;
    }

    // ---- swapped QK^T, K loads shared across both q-subtiles ----
    f32x4 acc[2][8];
    __builtin_amdgcn_s_setprio(1);
#pragma unroll
    for (int ct = 0; ct < 8; ++ct) {
        const _Float16* krow = kp + (size_t)(kbase + ct * 16 + lr) * D + lg * 8;
        f16x8 kv0 = *(const f16x8*)(krow);
        f16x8 kv1 = *(const f16x8*)(krow + 32);
#pragma unroll
        for (int t = 0; t < 2; ++t) {
            f32x4 a = {0.f, 0.f, 0.f, 0.f};
            a = MFMA16(kv0, qf[t][0], a);
            a = MFMA16(kv1, qf[t][1], a);
            acc[t][ct] = a;
        }
    }
    __builtin_amdgcn_s_setprio(0);

    // ---- bias*mask apply ----
    const _Float16* bmr = bmp_g + ((size_t)(b * 32 + qt) * 8 + wave) * 4096;
#pragma unroll
    for (int t = 0; t < 2; ++t) {
#pragma unroll
        for (int g = 0; g < 4; ++g) {
            f16x8 bv = *(const f16x8*)(bmr + t * 2048 + g * 512 + lane * 8);
#pragma unroll
            for (int s = 0; s < 8; ++s) {
                const int slot = g * 8 + s;
                float tt = (float)bv[s];
                float a = acc[t][slot >> 2][slot & 3];
                acc[t][slot >> 2][slot & 3] = (tt >= 0.f) ? a * tt : -INFINITY;
            }
        }
    }

    // ---- two independent in-register softmax chains (ILP) ----
    float m[2], ls[2];
#pragma unroll
    for (int t = 0; t < 2; ++t) m[t] = -INFINITY;
#pragma unroll
    for (int ct = 0; ct < 8; ++ct)
#pragma unroll
        for (int t = 0; t < 2; ++t)
#pragma unroll
            for (int r = 0; r < 4; ++r) m[t] = fmaxf(m[t], acc[t][ct][r]);
#pragma unroll
    for (int t = 0; t < 2; ++t) {
        m[t] = fmaxf(m[t], __shfl_xor(m[t], 16));
        m[t] = fmaxf(m[t], __shfl_xor(m[t], 32));
        m[t] = fmaxf(m[t], -10000.0f);        // guard all-masked chunk
        ls[t] = 0.f;
    }
#pragma unroll
    for (int ct = 0; ct < 8; ++ct)
#pragma unroll
        for (int t = 0; t < 2; ++t)
#pragma unroll
            for (int r = 0; r < 4; ++r) {
                float p = __expf(acc[t][ct][r] - m[t]);
                acc[t][ct][r] = p;
                ls[t] += p;
            }
#pragma unroll
    for (int t = 0; t < 2; ++t) {
        ls[t] += __shfl_xor(ls[t], 16);
        ls[t] += __shfl_xor(ls[t], 32);
    }

    // ---- cross-wave reduction (separate red buffer; 2 barriers total) ----
    if (lg == 0) {
#pragma unroll
        for (int t = 0; t < 2; ++t) {
            red[wave][t * 16 + lr][0] = m[t];
            red[wave][t * 16 + lr][1] = ls[t];
        }
    }
    __syncthreads();                          // barrier 1: red ready

    float scale[2];
#pragma unroll
    for (int t = 0; t < 2; ++t) {
        const int row = t * 16 + lr;
        float M = -INFINITY;
#pragma unroll
        for (int w = 0; w < 8; ++w) M = fmaxf(M, red[w][row][0]);
        float denom = 0.f;
#pragma unroll
        for (int w = 0; w < 8; ++w) denom += red[w][row][1] * __expf(red[w][row][0] - M);
        denom = fmaxf(denom, 1e-37f);
        scale[t] = __expf(m[t] - M) / denom;
    }

    // ---- P -> LDS fp16 (normalized) ----
#pragma unroll
    for (int t = 0; t < 2; ++t)
#pragma unroll
        for (int ct = 0; ct < 8; ++ct) {
            f16x4 pv;
#pragma unroll
            for (int r = 0; r < 4; ++r) pv[r] = (_Float16)(acc[t][ct][r] * scale[t]);
            *(f16x4*)&plds[swzh(t * 16 + lr, kbase + ct * 16 + 4 * lg)] = pv;
        }
    __syncthreads();                          // barrier 2: P ready

    // ---- V-ring prefetch issued BEFORE score stores: first 8 V-loads sit
    // ahead of the NT stores in vmcnt order, so early PV MFMAs don't wait on
    // the HBM store drain ----
    const int qsub = wave >> 2;
    const int d0   = (wave & 3) * 16;
    const _Float16* vrow = vtf_g + (size_t)bh * D * L + (size_t)(d0 + lr) * L;
    f16x8 vr[8];
#pragma unroll
    for (int j = 0; j < 8; ++j) {
        vr[j] = *(const f16x8*)(vrow + j * 32 + lg * 8);
    }

    // ---- score store: wave w owns rows 4w..4w+3; NT 1KB/instr (contiguous) ----
    const int row0 = wave * 4;
    float* srow0 = outg + OUT_ELEMS + (size_t)bh * L * L + (size_t)(q0 + row0) * L;
#pragma unroll
    for (int rr = 0; rr < 4; ++rr) {
#pragma unroll
        for (int mt = 0; mt < 4; ++mt) {
            const int col = mt * 256 + lane * 4;
            f16x4 pv = *(const f16x4*)&plds[swzh(row0 + rr, col)];
            f32x4 o = {(float)pv[0], (float)pv[1], (float)pv[2], (float)pv[3]};
            __builtin_nontemporal_store(o, (f32x4*)(srow0 + (size_t)rr * L + col));
        }
    }

    // ---- PV: wave w -> (q-subtile w>>2, d cols 16*(w&3)..+16); depth-8 ring ----
    f32x4 oacc = {0.f, 0.f, 0.f, 0.f};
    __builtin_amdgcn_s_setprio(1);
#pragma unroll
    for (int i = 0; i < 32; ++i) {
        const int s = i & 7;
        f16x8 pa = *(const f16x8*)&plds[swzh(qsub * 16 + lr, i * 32 + lg * 8)];
        oacc = MFMA16(pa, vr[s], oacc);
        if (i < 24) {
            vr[s] = *(const f16x8*)(vrow + (i + 8) * 32 + lg * 8);
        }
    }
    __builtin_amdgcn_s_setprio(0);
#pragma unroll
    for (int r = 0; r < 4; ++r) {
        __builtin_nontemporal_store(
            oacc[r], outg + ((size_t)bh * L + q0 + qsub * 16 + lg * 4 + r) * D + d0 + lr);
    }
}

extern "C" void kernel_launch(void* const* d_in, const int* in_sizes, int n_in,
                              void* d_out, int out_size, void* d_ws, size_t ws_size,
                              hipStream_t stream) {
    const float* q    = (const float*)d_in[0];
    const float* k    = (const float*)d_in[1];
    const float* v    = (const float*)d_in[2];
    const float* bias = (const float*)d_in[3];
    const int*   mask = (const int*)d_in[4];
    float* out = (float*)d_out;

    const size_t need = (2 * PLANE + BMN) * sizeof(_Float16);   // ~50 MiB
    if (ws_size < need) return;               // empirically ws_size >= 64 MiB

    _Float16* kf  = (_Float16*)d_ws;          // [BH][L][D] fp16, pre-scaled 0.125
    _Float16* vtf = kf + PLANE;               // [BH][D][L] fp16
    _Float16* bmp = vtf + PLANE;              // permuted fp16 bias/mask plane

    hipLaunchKernelGGL(prep_all, dim3(8192), dim3(256), 0, stream,
                       k, v, bias, mask, kf, vtf, bmp);
    hipLaunchKernelGGL(attn_main, dim3(4096), dim3(512), 0, stream,
                       q, kf, vtf, bmp, out);
}